// Round 1
// baseline (5674.142 us; speedup 1.0000x reference)
//
#include <hip/hip_runtime.h>

// LSTM T=512 B=64 IN=512 H=512 L=2, fp32 in/out.
// Round 6: per-wave autonomous recurrence. 128 blocks (1/CU), 4 waves/block,
// wave = (bt batch-32-tile, kh K-half). A fragments loaded DIRECTLY from
// global (agent atomics) into VGPRs in MFMA layout -- no hstage LDS, no
// staging barriers. Unit1's two input halves (h0_t via Wx1, h1_{t-1} via Wh1)
// now resolve in parallel waves instead of two serial block-wide stages.
// Per step: wave{poll flags -> 64 b64 loads -> 32 MFMA} -> ldsg partials ->
// syncthreads -> epilogue (gate math, direct packed-bf16 publish) ->
// vmcnt(0) -> syncthreads -> lane0 flag.

typedef unsigned short u16;
typedef unsigned int u32;
typedef unsigned long long u64;
typedef __attribute__((ext_vector_type(8))) short bf16x8;
typedef __attribute__((ext_vector_type(4))) float floatx4;
typedef __attribute__((ext_vector_type(16))) float floatx16;

#define T_ 512
#define B_ 64
#define H_ 512
#define BH (B_ * H_)

__device__ __forceinline__ u16 f2bf(float f) {
  u32 u = __float_as_uint(f);
  u32 r = (u + 0x7fffu + ((u >> 16) & 1u)) >> 16;  // RNE
  return (u16)r;
}

__device__ __forceinline__ float sigm(float x) { return 1.f / (1.f + __expf(-x)); }

__device__ __forceinline__ float tanh_(float x) {
  float ax = fabsf(x);
  float e = __expf(-2.f * ax);
  float t = (1.f - e) / (1.f + e);
  return copysignf(t, x);
}

// Wcat[l][row 0..2047][k 0..1023] bf16: k<512 from Wx, k>=512 from Wh.
__global__ void conv_w_kernel(const float* __restrict__ Wx, const float* __restrict__ Wh,
                              u16* __restrict__ Wcat) {
  int i = blockIdx.x * 256 + threadIdx.x;
  int base = i * 4;
  int k = base & 1023;
  int row = base >> 10;
  const float* src = (k < 512) ? (Wx + row * 512 + k) : (Wh + row * 512 + (k - 512));
  float4 v = *(const float4*)src;
  uint2 p;
  p.x = (u32)f2bf(v.x) | ((u32)f2bf(v.y) << 16);
  p.y = (u32)f2bf(v.z) | ((u32)f2bf(v.w) << 16);
  *(uint2*)(Wcat + base) = p;
}

__global__ void conv_x_kernel(const float4* __restrict__ x, u16* __restrict__ xb) {
  int i = blockIdx.x * 256 + threadIdx.x;
  float4 v = x[i];
  uint2 p;
  p.x = (u32)f2bf(v.x) | ((u32)f2bf(v.y) << 16);
  p.y = (u32)f2bf(v.z) | ((u32)f2bf(v.w) << 16);
  *(uint2*)(xb + i * 4) = p;
}

__global__ void init_flags(u32* flags) {
  if (threadIdx.x < 128) flags[threadIdx.x] = 0;
}

__device__ __forceinline__ u32 aload32(const u32* p) {
  return __hip_atomic_load(p, __ATOMIC_RELAXED, __HIP_MEMORY_SCOPE_AGENT);
}
__device__ __forceinline__ u64 aload64(const u64* p) {
  return __hip_atomic_load(p, __ATOMIC_RELAXED, __HIP_MEMORY_SCOPE_AGENT);
}
__device__ __forceinline__ void astore32(u32* p, u32 v) {
  __hip_atomic_store(p, v, __ATOMIC_RELAXED, __HIP_MEMORY_SCOPE_AGENT);
}

// Whole-wave poll: lane l watches f[l] (64 producer flags), exit when all >= target.
__device__ __forceinline__ void wave_wait(const u32* f, u32 target, int lane) {
  while (!__all((int)(aload32(f + lane) >= target))) __builtin_amdgcn_s_sleep(1);
}

// h-half MFMA: A fragments straight from global h matrix [64][512] bf16.
// Per lane: row = bt*32 + l31 (fixed), frag i = 16B at k = i*16 + lh*8.
// 64 independent 8B coherent loads in flight, then 32 MFMAs as data lands.
__device__ __forceinline__ void mfma_h(const u16* __restrict__ hmat, int row, int lh,
                                       const bf16x8* w, floatx16& acc) {
  const u64* p = (const u64*)(hmat + row * 512 + lh * 8);
  u64 q[64];
#pragma unroll
  for (int i = 0; i < 32; ++i) {
    q[2 * i] = aload64(p + i * 4);
    q[2 * i + 1] = aload64(p + i * 4 + 1);
  }
#pragma unroll
  for (int i = 0; i < 32; ++i) {
    union {
      u64 qq[2];
      bf16x8 v;
    } u;
    u.qq[0] = q[2 * i];
    u.qq[1] = q[2 * i + 1];
    acc = __builtin_amdgcn_mfma_f32_32x32x16_bf16(u.v, w[i], acc, 0, 0, 0);
  }
}

// 128 blocks x 256 threads (1 block/CU). unit=blockIdx&1, cg=blockIdx>>1.
// Wave: bt=wave&1 (batch 32-tile), kh=wave>>1 (K-half). Logical W row
// rp = gate*8 + localcol (0..31). flags[2][64] = per-block step counters.
__global__ __launch_bounds__(256, 1) void lstm_persist(
    const u16* __restrict__ Wcat, const float* __restrict__ bh,
    const u16* __restrict__ xb, u16* __restrict__ h0s, u16* __restrict__ h1s,
    u32* flags, float* __restrict__ out) {
  const int unit = blockIdx.x & 1;
  const int cg = blockIdx.x >> 1;
  const int colbase = cg * 8;
  const int tid = threadIdx.x;
  const int wave = tid >> 6;
  const int bt = wave & 1;
  const int kh = wave >> 1;
  const int lane = tid & 63;
  const int l31 = lane & 31;
  const int lh = lane >> 5;

  __shared__ float ldsg[4 * 32 * 36];  // 18,432 B [bt*2+kh][Wrow 32][batch 36p]

  // ---- W fragments into VGPRs (loop-invariant). B[k][col]: col=lane&31 -> W
  // row rp; k = kh*512 + i*16 + lh*8 + j (8 contiguous k -> one b128).
  bf16x8 w[32];
  {
    const int rp = l31;
    const u16* wbase = Wcat + ((size_t)unit * 2048 + (rp >> 3) * 512 + colbase + (rp & 7)) * 1024 +
                       kh * 512 + lh * 8;
#pragma unroll
    for (int i = 0; i < 32; ++i) w[i] = *(const bf16x8*)(wbase + i * 16);
  }

  // epilogue ownership: batch eb = tid>>2, 2 cols ec..ec+1 (ec=(tid&3)*2)
  const int eb = tid >> 2;
  const int ebt = eb >> 5;
  const int eb32 = eb & 31;
  const int ec = (tid & 3) * 2;
  float bias[4][2];
#pragma unroll
  for (int g = 0; g < 4; ++g)
#pragma unroll
    for (int cc = 0; cc < 2; ++cc)
      bias[g][cc] = bh[unit * 2048 + g * 512 + colbase + ec + cc];

  float creg[2] = {0.f, 0.f};

  const u32* f0 = flags;
  const u32* f1 = flags + 64;
  u32* myflag = flags + unit * 64 + cg;

  const size_t out_h_base = (size_t)T_ * BH;
  const size_t out_c_base = out_h_base + 2 * (size_t)BH;

  const int arow = bt * 32 + l31;

  for (int t = 0; t < T_; ++t) {
    floatx16 acc = {0.f, 0.f, 0.f, 0.f, 0.f, 0.f, 0.f, 0.f,
                    0.f, 0.f, 0.f, 0.f, 0.f, 0.f, 0.f, 0.f};

    if (unit == 0) {
      if (kh == 0) {
        // x-half: no dependency, plain loads from pre-converted xb.
        const u16* abase = xb + (size_t)t * BH + (size_t)arow * 512 + lh * 8;
#pragma unroll
        for (int i = 0; i < 32; ++i) {
          bf16x8 a = *(const bf16x8*)(abase + i * 16);
          acc = __builtin_amdgcn_mfma_f32_32x32x16_bf16(a, w[i], acc, 0, 0, 0);
        }
        // slot-reuse guard: unit1 must have consumed h0_{t-4} (published f1 >= t-3)
        // before this block's epilogue overwrites slot t&3. Barrier below gates all.
        if (bt == 0 && t >= 4) wave_wait(f1, (u32)(t - 3), lane);
      } else if (t > 0) {
        // h0_{t-1} half: the layer-0 recurrence (critical chain).
        wave_wait(f0, (u32)t, lane);
        mfma_h(h0s + (size_t)((t - 1) & 3) * BH, arow, lh, w, acc);
      }
    } else {
      if (kh == 1) {
        // h1_{t-1} half (Wh1): own-layer recurrence.
        if (t > 0) {
          wave_wait(f1, (u32)t, lane);
          mfma_h(h1s + (size_t)((t - 1) & 3) * BH, arow, lh, w, acc);
        }
      } else {
        // h0_t half (Wx1): the cross-layer hop, runs CONCURRENTLY with kh1.
        wave_wait(f0, (u32)(t + 1), lane);
        mfma_h(h0s + (size_t)(t & 3) * BH, arow, lh, w, acc);
      }
    }

    // ---- write kh partials: C/D row=(reg&3)+8*(reg>>2)+4*lh, col=lane&31 ----
    {
      float* lg = ldsg + (bt * 2 + kh) * 1152 + l31 * 36 + 4 * lh;
#pragma unroll
      for (int rg = 0; rg < 4; ++rg)
        *(floatx4*)(lg + 8 * rg) =
            floatx4{acc[rg * 4 + 0], acc[rg * 4 + 1], acc[rg * 4 + 2], acc[rg * 4 + 3]};
    }
    __syncthreads();

    // ---- epilogue: sum kh partials + bias, gate math, c in regs ----
    float hn[2], cn[2];
#pragma unroll
    for (int cc = 0; cc < 2; ++cc) {
      int c = ec + cc;
      float pi = ldsg[(ebt * 2 + 0) * 1152 + (0 * 8 + c) * 36 + eb32] +
                 ldsg[(ebt * 2 + 1) * 1152 + (0 * 8 + c) * 36 + eb32] + bias[0][cc];
      float pf = ldsg[(ebt * 2 + 0) * 1152 + (1 * 8 + c) * 36 + eb32] +
                 ldsg[(ebt * 2 + 1) * 1152 + (1 * 8 + c) * 36 + eb32] + bias[1][cc];
      float pg = ldsg[(ebt * 2 + 0) * 1152 + (2 * 8 + c) * 36 + eb32] +
                 ldsg[(ebt * 2 + 1) * 1152 + (2 * 8 + c) * 36 + eb32] + bias[2][cc];
      float po = ldsg[(ebt * 2 + 0) * 1152 + (3 * 8 + c) * 36 + eb32] +
                 ldsg[(ebt * 2 + 1) * 1152 + (3 * 8 + c) * 36 + eb32] + bias[3][cc];
      float ig = sigm(pi);
      float fg = sigm(pf);
      float gg = tanh_(pg);
      float og = sigm(po);
      cn[cc] = fg * creg[cc] + ig * gg;
      hn[cc] = og * tanh_(cn[cc]);
      creg[cc] = cn[cc];
    }

    // ---- direct publish: each thread stores its packed bf16 pair ----
    u16* hout = (unit == 0 ? h0s : h1s) + (size_t)(t & 3) * BH;
    astore32((u32*)(hout + (size_t)eb * 512 + colbase + ec),
             (u32)f2bf(hn[0]) | ((u32)f2bf(hn[1]) << 16));

    // ---- off-chain d_out stores (drain together with publish) ----
    size_t sidx = (size_t)eb * H_ + colbase + ec;
    if (unit == 1)
      *(float2*)(out + (size_t)t * BH + sidx) = make_float2(hn[0], hn[1]);
    if (t == T_ - 1) {
      *(float2*)(out + out_h_base + (size_t)unit * BH + sidx) = make_float2(hn[0], hn[1]);
      *(float2*)(out + out_c_base + (size_t)unit * BH + sidx) = make_float2(cn[0], cn[1]);
    }

    asm volatile("s_waitcnt vmcnt(0)" ::: "memory");
    __syncthreads();
    if (tid == 0) astore32(myflag, (u32)(t + 1));
  }
}

extern "C" void kernel_launch(void* const* d_in, const int* in_sizes, int n_in,
                              void* d_out, int out_size, void* d_ws, size_t ws_size,
                              hipStream_t stream) {
  const float* x = (const float*)d_in[0];
  const float* Wx = (const float*)d_in[1];
  const float* Wh = (const float*)d_in[2];
  const float* bh = (const float*)d_in[3];
  float* out = (float*)d_out;
  char* ws = (char*)d_ws;

  u16* Wcat = (u16*)ws;                                  // 8,388,608 B
  u16* xb = (u16*)(ws + 8388608);                        // 33,554,432 B
  u16* h0s = (u16*)(ws + 8388608 + 33554432);            // 262,144 B (4 slots)
  u16* h1s = (u16*)(ws + 8388608 + 33554432 + 262144);   // 262,144 B
  u32* flags = (u32*)(ws + 8388608 + 33554432 + 2 * 262144);  // 512 B

  conv_w_kernel<<<4096, 256, 0, stream>>>(Wx, Wh, Wcat);
  conv_x_kernel<<<16384, 256, 0, stream>>>((const float4*)x, xb);
  init_flags<<<1, 128, 0, stream>>>(flags);
  lstm_persist<<<128, 256, 0, stream>>>(Wcat, bh, xb, h0s, h1s, flags, out);
}

// Round 2
// 3709.908 us; speedup vs baseline: 1.5295x; 1.5295x over previous
//
#include <hip/hip_runtime.h>

// LSTM T=512 B=64 IN=512 H=512 L=2, fp32 in/out.
// Round 7: transposed publish layout. h (and x) are stored in MFMA-fragment
// order hT[bt(2)][plane(2)][i(32)][lane(64)] x 8B, so consumer waves load
// their A fragments with dense coalesced aload64 (base + i*512 + lane*8) --
// no LDS staging, no staging barriers, no scatter. Producers write the
// layout for free (each block owns 8 cols = one (i,lh) slot; one u32
// store/thread). Unit1's two input halves resolve in parallel waves.
// Per step: wave{poll flags -> 64 dense aload64 -> 32 MFMA} -> ldsg partials
// -> syncthreads -> epilogue -> publish -> vmcnt(0) -> syncthreads ->
// lane0 flag -> out stores (drain off-chain).

typedef unsigned short u16;
typedef unsigned int u32;
typedef unsigned long long u64;
typedef __attribute__((ext_vector_type(8))) short bf16x8;
typedef __attribute__((ext_vector_type(4))) float floatx4;
typedef __attribute__((ext_vector_type(16))) float floatx16;

#define T_ 512
#define B_ 64
#define H_ 512
#define BH (B_ * H_)

__device__ __forceinline__ u16 f2bf(float f) {
  u32 u = __float_as_uint(f);
  u32 r = (u + 0x7fffu + ((u >> 16) & 1u)) >> 16;  // RNE
  return (u16)r;
}

__device__ __forceinline__ float sigm(float x) { return 1.f / (1.f + __expf(-x)); }

__device__ __forceinline__ float tanh_(float x) {
  float ax = fabsf(x);
  float e = __expf(-2.f * ax);
  float t = (1.f - e) / (1.f + e);
  return copysignf(t, x);
}

// Wcat[l][row 0..2047][k 0..1023] bf16: k<512 from Wx, k>=512 from Wh.
__global__ void conv_w_kernel(const float* __restrict__ Wx, const float* __restrict__ Wh,
                              u16* __restrict__ Wcat) {
  int i = blockIdx.x * 256 + threadIdx.x;
  int base = i * 4;
  int k = base & 1023;
  int row = base >> 10;
  const float* src = (k < 512) ? (Wx + row * 512 + k) : (Wh + row * 512 + (k - 512));
  float4 v = *(const float4*)src;
  uint2 p;
  p.x = (u32)f2bf(v.x) | ((u32)f2bf(v.y) << 16);
  p.y = (u32)f2bf(v.z) | ((u32)f2bf(v.w) << 16);
  *(uint2*)(Wcat + base) = p;
}

// xT[t][bt][plane][i][lane] 8B pieces: piece = x_bf16[t][bt*32+(lane&31)]
// [i*16+(lane>>5)*8+plane*4 .. +4). Consumer loads are dense per fragment.
__global__ void conv_x_kernel(const float* __restrict__ x, u16* __restrict__ xb) {
  int p = blockIdx.x * 256 + threadIdx.x;  // 4,194,304 pieces
  int lane = p & 63;
  int i = (p >> 6) & 31;
  int plane = (p >> 11) & 1;
  int bt = (p >> 12) & 1;
  int t = p >> 13;
  int r = bt * 32 + (lane & 31);
  int k0 = i * 16 + (lane >> 5) * 8 + plane * 4;
  float4 v = *(const float4*)(x + ((size_t)(t * 64 + r) * 512 + k0));
  uint2 q;
  q.x = (u32)f2bf(v.x) | ((u32)f2bf(v.y) << 16);
  q.y = (u32)f2bf(v.z) | ((u32)f2bf(v.w) << 16);
  *(uint2*)(xb + (size_t)p * 4) = q;
}

__global__ void init_flags(u32* flags) {
  if (threadIdx.x < 128) flags[threadIdx.x] = 0;
}

__device__ __forceinline__ u32 aload32(const u32* p) {
  return __hip_atomic_load(p, __ATOMIC_RELAXED, __HIP_MEMORY_SCOPE_AGENT);
}
__device__ __forceinline__ u64 aload64(const u64* p) {
  return __hip_atomic_load(p, __ATOMIC_RELAXED, __HIP_MEMORY_SCOPE_AGENT);
}
__device__ __forceinline__ void astore32(u32* p, u32 v) {
  __hip_atomic_store(p, v, __ATOMIC_RELAXED, __HIP_MEMORY_SCOPE_AGENT);
}

// Whole-wave poll: lane l watches f[l] (64 producer flags), exit when all >= target.
__device__ __forceinline__ void wave_wait(const u32* f, u32 target, int lane) {
  while (!__all((int)(aload32(f + lane) >= target))) __builtin_amdgcn_s_sleep(1);
}

// Dense fragment loads from transposed h matrix (hp = u64 base of 64KB slot):
// fragment i: q0 = [bt][0][i][lane], q1 = [bt][1][i][lane]. Both streams are
// contiguous 512B per instr across the wave.
__device__ __forceinline__ void mfma_hT(const u64* __restrict__ hp, int bt, int lane,
                                        const bf16x8* w, floatx16& acc) {
  const u64* p = hp + (size_t)bt * 4096 + lane;
  u64 q[64];
#pragma unroll
  for (int i = 0; i < 32; ++i) {
    q[2 * i] = aload64(p + i * 64);
    q[2 * i + 1] = aload64(p + 2048 + i * 64);
  }
#pragma unroll
  for (int i = 0; i < 32; ++i) {
    union {
      u64 qq[2];
      bf16x8 v;
    } u;
    u.qq[0] = q[2 * i];
    u.qq[1] = q[2 * i + 1];
    acc = __builtin_amdgcn_mfma_f32_32x32x16_bf16(u.v, w[i], acc, 0, 0, 0);
  }
}

// 128 blocks x 256 threads (1 block/CU). unit=blockIdx&1, cg=blockIdx>>1.
// Wave: bt=wave&1 (batch 32-tile), kh=wave>>1 (K-half). Logical W row
// rp = gate*8 + localcol (0..31). flags[2][64] = per-block step counters.
__global__ __launch_bounds__(256, 1) void lstm_persist(
    const u16* __restrict__ Wcat, const float* __restrict__ bh,
    const u16* __restrict__ xb, u16* __restrict__ h0s, u16* __restrict__ h1s,
    u32* flags, float* __restrict__ out) {
  const int unit = blockIdx.x & 1;
  const int cg = blockIdx.x >> 1;
  const int colbase = cg * 8;
  const int tid = threadIdx.x;
  const int wave = tid >> 6;
  const int bt = wave & 1;
  const int kh = wave >> 1;
  const int lane = tid & 63;
  const int l31 = lane & 31;
  const int lh = lane >> 5;

  __shared__ float ldsg[4 * 32 * 36];  // 18,432 B [bt*2+kh][Wrow 32][batch 36p]

  // ---- W fragments into VGPRs (loop-invariant). B[k][col]: col=lane&31 -> W
  // row rp; k = kh*512 + i*16 + lh*8 + j (8 contiguous k -> one b128).
  bf16x8 w[32];
  {
    const int rp = l31;
    const u16* wbase = Wcat + ((size_t)unit * 2048 + (rp >> 3) * 512 + colbase + (rp & 7)) * 1024 +
                       kh * 512 + lh * 8;
#pragma unroll
    for (int i = 0; i < 32; ++i) w[i] = *(const bf16x8*)(wbase + i * 16);
  }

  // epilogue ownership: batch eb = tid>>2, 2 cols ec..ec+1 (ec=(tid&3)*2)
  const int eb = tid >> 2;
  const int ebt = eb >> 5;
  const int eb32 = eb & 31;
  const int ec = (tid & 3) * 2;
  float bias[4][2];
#pragma unroll
  for (int g = 0; g < 4; ++g)
#pragma unroll
    for (int cc = 0; cc < 2; ++cc)
      bias[g][cc] = bh[unit * 2048 + g * 512 + colbase + ec + cc];

  // publish address (u32 index into 64KB hT slot), constant per thread:
  // [bt]*8192 + [plane]*4096 + [i]*128 + [lane]*2 + (ec&3)>>1
  const int pub_idx = (ebt << 13) + ((ec >> 2) << 12) + ((colbase >> 4) << 7) +
                      (((eb32) | (((colbase >> 3) & 1) << 5)) << 1) + ((ec & 3) >> 1);

  float creg[2] = {0.f, 0.f};

  const u32* f0 = flags;
  const u32* f1 = flags + 64;
  u32* myflag = flags + unit * 64 + cg;

  const size_t out_h_base = (size_t)T_ * BH;
  const size_t out_c_base = out_h_base + 2 * (size_t)BH;

  for (int t = 0; t < T_; ++t) {
    floatx16 acc = {0.f, 0.f, 0.f, 0.f, 0.f, 0.f, 0.f, 0.f,
                    0.f, 0.f, 0.f, 0.f, 0.f, 0.f, 0.f, 0.f};

    if (unit == 0) {
      if (kh == 0) {
        // x-half: dense plain loads from transposed xb (no dependency).
        const u64* xp = (const u64*)xb + (size_t)t * 8192 + (size_t)bt * 4096 + lane;
#pragma unroll
        for (int i = 0; i < 32; ++i) {
          union {
            u64 qq[2];
            bf16x8 v;
          } u;
          u.qq[0] = xp[i * 64];
          u.qq[1] = xp[2048 + i * 64];
          acc = __builtin_amdgcn_mfma_f32_32x32x16_bf16(u.v, w[i], acc, 0, 0, 0);
        }
        // slot-reuse guard: unit1 must have consumed h0_{t-4} (published f1 >=
        // t-3) before this block's epilogue overwrites slot t&3. The ldsg
        // barrier below gates the whole block on this wave's wait.
        if (bt == 0 && t >= 4) wave_wait(f1, (u32)(t - 3), lane);
      } else if (t > 0) {
        // h0_{t-1} half: the layer-0 recurrence (critical chain).
        wave_wait(f0, (u32)t, lane);
        mfma_hT((const u64*)h0s + (size_t)((t - 1) & 3) * 8192, bt, lane, w, acc);
      }
    } else {
      if (kh == 1) {
        // h1_{t-1} half (Wh1): own-layer recurrence.
        if (t > 0) {
          wave_wait(f1, (u32)t, lane);
          mfma_hT((const u64*)h1s + (size_t)((t - 1) & 3) * 8192, bt, lane, w, acc);
        }
      } else {
        // h0_t half (Wx1): the cross-layer hop, runs CONCURRENTLY with kh1.
        wave_wait(f0, (u32)(t + 1), lane);
        mfma_hT((const u64*)h0s + (size_t)(t & 3) * 8192, bt, lane, w, acc);
      }
    }

    // ---- write kh partials: C/D row=(reg&3)+8*(reg>>2)+4*lh, col=lane&31 ----
    {
      float* lg = ldsg + (bt * 2 + kh) * 1152 + l31 * 36 + 4 * lh;
#pragma unroll
      for (int rg = 0; rg < 4; ++rg)
        *(floatx4*)(lg + 8 * rg) =
            floatx4{acc[rg * 4 + 0], acc[rg * 4 + 1], acc[rg * 4 + 2], acc[rg * 4 + 3]};
    }
    __syncthreads();

    // ---- epilogue: sum kh partials + bias, gate math, c in regs ----
    float hn[2], cn[2];
#pragma unroll
    for (int cc = 0; cc < 2; ++cc) {
      int c = ec + cc;
      float pi = ldsg[(ebt * 2 + 0) * 1152 + (0 * 8 + c) * 36 + eb32] +
                 ldsg[(ebt * 2 + 1) * 1152 + (0 * 8 + c) * 36 + eb32] + bias[0][cc];
      float pf = ldsg[(ebt * 2 + 0) * 1152 + (1 * 8 + c) * 36 + eb32] +
                 ldsg[(ebt * 2 + 1) * 1152 + (1 * 8 + c) * 36 + eb32] + bias[1][cc];
      float pg = ldsg[(ebt * 2 + 0) * 1152 + (2 * 8 + c) * 36 + eb32] +
                 ldsg[(ebt * 2 + 1) * 1152 + (2 * 8 + c) * 36 + eb32] + bias[2][cc];
      float po = ldsg[(ebt * 2 + 0) * 1152 + (3 * 8 + c) * 36 + eb32] +
                 ldsg[(ebt * 2 + 1) * 1152 + (3 * 8 + c) * 36 + eb32] + bias[3][cc];
      float ig = sigm(pi);
      float fg = sigm(pf);
      float gg = tanh_(pg);
      float og = sigm(po);
      cn[cc] = fg * creg[cc] + ig * gg;
      hn[cc] = og * tanh_(cn[cc]);
      creg[cc] = cn[cc];
    }

    // ---- publish into transposed layout: one u32 per thread ----
    u32* hout32 = (u32*)((unit == 0 ? h0s : h1s) + (size_t)(t & 3) * BH);
    astore32(hout32 + pub_idx, (u32)f2bf(hn[0]) | ((u32)f2bf(hn[1]) << 16));

    asm volatile("s_waitcnt vmcnt(0)" ::: "memory");
    __syncthreads();
    if (tid == 0) astore32(myflag, (u32)(t + 1));

    // ---- off-chain d_out stores AFTER flag release (drain hidden) ----
    size_t sidx = (size_t)eb * H_ + colbase + ec;
    if (unit == 1)
      *(float2*)(out + (size_t)t * BH + sidx) = make_float2(hn[0], hn[1]);
    if (t == T_ - 1) {
      *(float2*)(out + out_h_base + (size_t)unit * BH + sidx) = make_float2(hn[0], hn[1]);
      *(float2*)(out + out_c_base + (size_t)unit * BH + sidx) = make_float2(cn[0], cn[1]);
    }
  }
}

extern "C" void kernel_launch(void* const* d_in, const int* in_sizes, int n_in,
                              void* d_out, int out_size, void* d_ws, size_t ws_size,
                              hipStream_t stream) {
  const float* x = (const float*)d_in[0];
  const float* Wx = (const float*)d_in[1];
  const float* Wh = (const float*)d_in[2];
  const float* bh = (const float*)d_in[3];
  float* out = (float*)d_out;
  char* ws = (char*)d_ws;

  u16* Wcat = (u16*)ws;                                  // 8,388,608 B
  u16* xb = (u16*)(ws + 8388608);                        // 33,554,432 B
  u16* h0s = (u16*)(ws + 8388608 + 33554432);            // 262,144 B (4 slots)
  u16* h1s = (u16*)(ws + 8388608 + 33554432 + 262144);   // 262,144 B
  u32* flags = (u32*)(ws + 8388608 + 33554432 + 2 * 262144);  // 512 B

  conv_w_kernel<<<4096, 256, 0, stream>>>(Wx, Wh, Wcat);
  conv_x_kernel<<<16384, 256, 0, stream>>>(x, xb);
  init_flags<<<1, 128, 0, stream>>>(flags);
  lstm_persist<<<128, 256, 0, stream>>>(Wcat, bh, xb, h0s, h1s, flags, out);
}